// Round 9
// baseline (175.758 us; speedup 1.0000x reference)
//
#include <hip/hip_runtime.h>

#define PP 16
#define DD 64
#define RR 32
#define KK 64
#define NBT 4096   // B*T

#define LOG2E 1.4426950408889634f
#define LN2   0.6931471805599453f
#define D2_CUT 25.0f   // keep pairs with d2 <= d2min + CUT; error <= omega_max*e^-25*ln2

static __device__ __forceinline__ float fast_log2(float x) { return __builtin_amdgcn_logf(x); }
static __device__ __forceinline__ float fast_exp2(float x) { return __builtin_amdgcn_exp2f(x); }
static __device__ __forceinline__ float fast_rcp(float x)  { return __builtin_amdgcn_rcpf(x); }

// One block, 1024 threads: thread t=(r,s). Stages c into LDS (transposed, padded),
// computes cc[r]=||c_r||^2, finds d2min over r<s, compacts pairs with
// d2 <= d2min+CUT into plist as (omega, int(r*32+s)). Also zeroes the tree-reduce
// counters (gcnt[64], fcnt) — kernel-boundary flush makes them visible to sheaf2.
__global__ __launch_bounds__(1024) void prune_kernel(const float* __restrict__ c,
                                                     float* __restrict__ cc,
                                                     int* __restrict__ npairs,
                                                     float2* __restrict__ plist,
                                                     int* __restrict__ gcnt,
                                                     int* __restrict__ fcnt) {
    __shared__ float2 sm_cT2[32 * 33];   // [d2][r], pad 33 -> conflict-free
    __shared__ float red[16];
    __shared__ float dmin_sh;
    __shared__ int cnt;
    const int t = threadIdx.x;

    {
        const float2* c2 = (const float2*)c;
        int rr = t >> 5, d2i = t & 31;
        sm_cT2[d2i * 33 + rr] = c2[t];
    }
    if (t == 0) cnt = 0;
    if (t < 64) gcnt[t] = 0;
    if (t == 64) *fcnt = 0;
    __syncthreads();

    const int r = t >> 5, s = t & 31;
    const bool active = s > r;
    float d2 = 0.f;
#pragma unroll
    for (int i = 0; i < 32; ++i) {
        float2 ca = sm_cT2[i * 33 + r];   // broadcast within half-wave
        float2 cb = sm_cT2[i * 33 + s];   // contiguous, 2-way (free)
        float dx = ca.x - cb.x, dy = ca.y - cb.y;
        d2 = fmaf(dx, dx, d2);
        d2 = fmaf(dy, dy, d2);
    }
    float dm = active ? d2 : 3.4e38f;
#pragma unroll
    for (int off = 32; off > 0; off >>= 1) dm = fminf(dm, __shfl_down(dm, off, 64));
    if ((t & 63) == 0) red[t >> 6] = dm;
    __syncthreads();
    if (t < 64) {
        float v = (t < 16) ? red[t] : 3.4e38f;
#pragma unroll
        for (int off = 8; off > 0; off >>= 1) v = fminf(v, __shfl_down(v, off, 64));
        if (t == 0) dmin_sh = v;
    }
    if (t < RR) {  // cc from LDS
        float a2 = 0.f;
#pragma unroll
        for (int i = 0; i < 32; ++i) {
            float2 cv = sm_cT2[i * 33 + t];
            a2 = fmaf(cv.x, cv.x, a2);
            a2 = fmaf(cv.y, cv.y, a2);
        }
        cc[t] = a2;
    }
    __syncthreads();
    const float dmin = dmin_sh;
    if (active && d2 <= dmin + D2_CUT) {
        int idx = atomicAdd(&cnt, 1);
        plist[idx] = make_float2(fast_exp2(-d2 * LOG2E), __int_as_float(t));
    }
    __syncthreads();
    if (t == 0) *npairs = cnt;
}

// r4 champion body + fused two-level tree reduction (reduce_kernel deleted):
// block bt stores its partial via atomicExch (coherent point), fences, bumps
// gcnt[bt>>6]; the 64th block of each group sums its 64 partials (atomic-loads,
// stale-proof per XCD-L2 non-coherence), writes gsum, bumps fcnt; the 64th group
// leader sums gsum -> out. Atomics spread over 64 lines: burst serialization
// ~0.3 us (vs r1/r2's ~25 us single-line tail).
__global__ __launch_bounds__(256) void sheaf2_kernel(
    const float* __restrict__ m, const float* __restrict__ w,
    const float* __restrict__ p, const float* __restrict__ c,
    const float* __restrict__ cc, const int* __restrict__ npairs,
    const float2* __restrict__ plist, float* __restrict__ partials,
    float* __restrict__ gsum, int* __restrict__ gcnt, int* __restrict__ fcnt,
    float* __restrict__ out) {
    // Alias zone: sm_pl (phase 4/5) overlaps cT2 (bytes 0-8447, phases 0-1) and
    // the staged m tile (bytes 8448-12543, phase 1). Lifetimes barrier-separated.
    __shared__ __align__(16) float2 sm_pl[RR * KK];  // 16384 B
    __shared__ float  sm_mass[PP * 36];              // 2304 B (pad 36: 16B-aligned rows)
    __shared__ float  sm_sw[PP];
    __shared__ float  sred[4];
    __shared__ int    s_last;

    float2* sm_cT2 = sm_pl;                  // 32*33 float2 = 8448 B
    float*  sm_m   = (float*)sm_pl + 2112;   // byte offset 8448, 4096 B (16B-aligned)

    const int tid = threadIdx.x;
    const int bt  = blockIdx.x;
    const int kq  = tid & 63;

    // ---- entry prefetch: p column (16 regs) + np; latency hides under stage+ph1 ----
    const float* pg_ = p + (size_t)bt * PP * KK + kq;
    float pcol[PP];
#pragma unroll
    for (int pi = 0; pi < PP; ++pi) pcol[pi] = pg_[pi * KK];
    const int np = __builtin_amdgcn_readfirstlane(*npairs);

    // ---- stage: c transposed (4 KB), m tile (4 KB coalesced float4), w ----
    {
        const float2* c2 = (const float2*)c;  // [r][d2], 1024 entries
#pragma unroll
        for (int it = 0; it < 4; ++it) {
            int idx = tid + 256 * it;
            sm_cT2[(idx & 31) * 33 + (idx >> 5)] = c2[idx];
        }
        const float4* m4 = (const float4*)(m + (size_t)bt * PP * DD);
        ((float4*)sm_m)[tid] = m4[tid];
        if (tid < PP) sm_sw[tid] = w[(size_t)bt * PP + tid];
    }
    __syncthreads();

    // ---- phase 1: logits[p][r] = 2*m.c - ||c||^2 (||m||^2 cancels in softmax) ----
    {
        const int r  = tid & 31;
        const int pg = tid >> 5;  // 0..7; handles pi = pg and pg+8
        const float4* m4a = (const float4*)(sm_m + pg * DD);
        const float4* m4b = (const float4*)(sm_m + (pg + 8) * DD);
        float ccr = cc[r];
        float acc0 = 0.f, acc1 = 0.f;
#pragma unroll
        for (int d4 = 0; d4 < 16; ++d4) {
            float2 ca = sm_cT2[(2 * d4) * 33 + r];
            float2 cb = sm_cT2[(2 * d4 + 1) * 33 + r];
            float4 ma = m4a[d4];
            float4 mb = m4b[d4];
            acc0 = fmaf(ma.x, ca.x, acc0); acc0 = fmaf(ma.y, ca.y, acc0);
            acc0 = fmaf(ma.z, cb.x, acc0); acc0 = fmaf(ma.w, cb.y, acc0);
            acc1 = fmaf(mb.x, ca.x, acc1); acc1 = fmaf(mb.y, ca.y, acc1);
            acc1 = fmaf(mb.z, cb.x, acc1); acc1 = fmaf(mb.w, cb.y, acc1);
        }
        sm_mass[pg * 36 + r]       = fmaf(2.f, acc0, -ccr);
        sm_mass[(pg + 8) * 36 + r] = fmaf(2.f, acc1, -ccr);
    }
    __syncthreads();

    // ---- phase 2: per-p softmax over r, all 256 threads ----
    {
        const int pidx = tid >> 4, l = tid & 15;
        float a = sm_mass[pidx * 36 + l];
        float b = sm_mass[pidx * 36 + l + 16];
        float mx = fmaxf(a, b);
#pragma unroll
        for (int off = 8; off > 0; off >>= 1) mx = fmaxf(mx, __shfl_xor(mx, off, 64));
        float ea = fast_exp2((a - mx) * LOG2E);
        float eb = fast_exp2((b - mx) * LOG2E);
        float ssum = ea + eb;
#pragma unroll
        for (int off = 8; off > 0; off >>= 1) ssum += __shfl_xor(ssum, off, 64);
        sm_mass[pidx * 36 + l]      = ea;
        sm_mass[pidx * 36 + l + 16] = eb;
        if (l == 0) sm_sw[pidx] = sm_sw[pidx] * fast_rcp(ssum);  // w / sum
    }
    __syncthreads();

    // ---- phase 3: mass[p][r] = e*sw[p] / (tot_r + eps); one full wave ----
    if (tid < 64) {
        const int r = tid & 31, h = tid >> 5;
        float ef[8];
        float tot = 0.f;
#pragma unroll
        for (int i = 0; i < 8; ++i) {
            ef[i] = sm_mass[(h * 8 + i) * 36 + r] * sm_sw[h * 8 + i];
            tot += ef[i];
        }
        tot += __shfl_xor(tot, 32, 64);
        float inv = fast_rcp(tot + 1e-6f);
#pragma unroll
        for (int i = 0; i < 8; ++i) sm_mass[(h * 8 + i) * 36 + r] = ef[i] * inv;
    }
    __syncthreads();

    // ---- phase 4: pbar[r][k]; store (pb, pb*log2 pb); overwrites cT2/m (dead) ----
    {
        const int wv = tid >> 6;
        const int r0 = wv * 8;
        float acc[8] = {0.f, 0.f, 0.f, 0.f, 0.f, 0.f, 0.f, 0.f};
#pragma unroll
        for (int pi = 0; pi < PP; ++pi) {
            float4 ma = *(const float4*)&sm_mass[pi * 36 + r0];      // wave-uniform bcast
            float4 mb = *(const float4*)&sm_mass[pi * 36 + r0 + 4];
            acc[0] = fmaf(pcol[pi], ma.x, acc[0]);
            acc[1] = fmaf(pcol[pi], ma.y, acc[1]);
            acc[2] = fmaf(pcol[pi], ma.z, acc[2]);
            acc[3] = fmaf(pcol[pi], ma.w, acc[3]);
            acc[4] = fmaf(pcol[pi], mb.x, acc[4]);
            acc[5] = fmaf(pcol[pi], mb.y, acc[5]);
            acc[6] = fmaf(pcol[pi], mb.z, acc[6]);
            acc[7] = fmaf(pcol[pi], mb.w, acc[7]);
        }
#pragma unroll
        for (int j = 0; j < 8; ++j) {
            float pb = acc[j];
            float l2 = fast_log2(pb + 1e-8f);
            sm_pl[(r0 + j) * KK + kq] = make_float2(pb, pb * l2);
        }
    }
    __syncthreads();

    // ---- phase 5: sum over pruned pairs; plist wave-uniform -> s_load; 2-pair ILP ----
    {
        const int wv = __builtin_amdgcn_readfirstlane(tid >> 6);
        float acc = 0.f;
        int i = wv;
        for (; i + 4 < np; i += 8) {
            float2 e0 = plist[i];
            float2 e1 = plist[i + 4];
            int rs0 = __float_as_int(e0.y);
            int rs1 = __float_as_int(e1.y);
            float2 a0 = sm_pl[(rs0 >> 5) * KK + kq];
            float2 b0 = sm_pl[(rs0 & 31) * KK + kq];
            float2 a1 = sm_pl[(rs1 >> 5) * KK + kq];
            float2 b1 = sm_pl[(rs1 & 31) * KK + kq];
            float s0 = a0.x + b0.x, t0 = a0.y + b0.y;
            float s1 = a1.x + b1.x, t1 = a1.y + b1.y;
            float lm0 = fast_log2(fmaf(0.5f, s0, 1e-8f));
            float lm1 = fast_log2(fmaf(0.5f, s1, 1e-8f));
            t0 = fmaf(-s0, lm0, t0);
            t1 = fmaf(-s1, lm1, t1);
            acc = fmaf(e0.x, t0, acc);
            acc = fmaf(e1.x, t1, acc);
        }
        if (i < np) {
            float2 e = plist[i];
            int rs = __float_as_int(e.y);
            float2 a = sm_pl[(rs >> 5) * KK + kq];
            float2 b = sm_pl[(rs & 31) * KK + kq];
            float sum = a.x + b.x;
            float t   = a.y + b.y;
            float lm  = fast_log2(fmaf(0.5f, sum, 1e-8f));
            t = fmaf(-sum, lm, t);
            acc = fmaf(e.x, t, acc);
        }
#pragma unroll
        for (int off = 32; off > 0; off >>= 1) acc += __shfl_down(acc, off, 64);
        if (kq == 0) sred[tid >> 6] = acc;
    }
    __syncthreads();

    // ---- fused tree reduction (replaces reduce_kernel) ----
    if (tid == 0) {
        float tot = (sred[0] + sred[1]) + (sred[2] + sred[3]);
        atomicExch(&partials[bt], tot * (0.5f * LN2 / 496.0f));  // coherent-point store
        __threadfence();                                          // release
        s_last = atomicAdd(&gcnt[bt >> 6], 1);
    }
    __syncthreads();
    if (s_last == 63 && tid < 64) {   // last block of this 64-block group
        __threadfence();              // acquire
        float v = atomicAdd(&partials[(bt >> 6) * 64 + tid], 0.0f);  // coherent load
#pragma unroll
        for (int off = 32; off > 0; off >>= 1) v += __shfl_down(v, off, 64);
        int o2 = 0;
        if (tid == 0) {
            atomicExch(&gsum[bt >> 6], v);
            __threadfence();
            o2 = atomicAdd(fcnt, 1);
        }
        o2 = __shfl(o2, 0, 64);
        if (o2 == 63) {               // last group: final sum
            __threadfence();
            float u = atomicAdd(&gsum[tid], 0.0f);
#pragma unroll
            for (int off = 32; off > 0; off >>= 1) u += __shfl_down(u, off, 64);
            if (tid == 0) out[0] = u;
        }
    }
}

extern "C" void kernel_launch(void* const* d_in, const int* in_sizes, int n_in,
                              void* d_out, int out_size, void* d_ws, size_t ws_size,
                              hipStream_t stream) {
    const float* m = (const float*)d_in[0];
    const float* w = (const float*)d_in[1];
    const float* p = (const float*)d_in[2];
    const float* c = (const float*)d_in[3];
    float* out = (float*)d_out;

    float* wsf      = (float*)d_ws;
    int*   npairs   = (int*)d_ws;            // [0]
    float* cc       = wsf + 64;              // 32 floats @ 256 B
    float2* plist   = (float2*)(wsf + 128);  // up to 496 float2 @ 512 B
    float* partials = wsf + 2048;            // 4096 floats @ 8 KB
    float* gsum     = wsf + 6144;            // 64 floats
    int*   gcnt     = (int*)(wsf + 6400);    // 64 ints
    int*   fcnt     = (int*)(wsf + 6464);    // 1 int

    prune_kernel<<<1, 1024, 0, stream>>>(c, cc, npairs, plist, gcnt, fcnt);
    sheaf2_kernel<<<NBT, 256, 0, stream>>>(m, w, p, c, cc, npairs, plist,
                                           partials, gsum, gcnt, fcnt, out);
}

// Round 10
// 99.887 us; speedup vs baseline: 1.7596x; 1.7596x over previous
//
#include <hip/hip_runtime.h>

#define PP 16
#define DD 64
#define RR 32
#define KK 64
#define NBT 4096   // B*T

#define LOG2E 1.4426950408889634f
#define LN2   0.6931471805599453f
#define D2_CUT 25.0f   // keep pairs with d2 <= d2min + CUT; error <= omega_max*e^-25*ln2

static __device__ __forceinline__ float fast_log2(float x) { return __builtin_amdgcn_logf(x); }
static __device__ __forceinline__ float fast_exp2(float x) { return __builtin_amdgcn_exp2f(x); }
static __device__ __forceinline__ float fast_rcp(float x)  { return __builtin_amdgcn_rcpf(x); }

// One block, 1024 threads: thread t=(r,s). Stages c into LDS (transposed, padded),
// computes cc[r]=||c_r||^2, finds d2min over r<s, compacts pairs with
// d2 <= d2min+CUT into plist as (omega, int(r*32+s)).
__global__ __launch_bounds__(1024) void prune_kernel(const float* __restrict__ c,
                                                     float* __restrict__ cc,
                                                     int* __restrict__ npairs,
                                                     float2* __restrict__ plist) {
    __shared__ float2 sm_cT2[32 * 33];   // [d2][r], pad 33 -> conflict-free
    __shared__ float red[16];
    __shared__ float dmin_sh;
    __shared__ int cnt;
    const int t = threadIdx.x;

    // stage c transposed: c2 is [r][d2] (32x32 float2), one entry per thread
    {
        const float2* c2 = (const float2*)c;
        int rr = t >> 5, d2i = t & 31;
        sm_cT2[d2i * 33 + rr] = c2[t];
    }
    if (t == 0) cnt = 0;
    __syncthreads();

    const int r = t >> 5, s = t & 31;
    const bool active = s > r;
    float d2 = 0.f;
#pragma unroll
    for (int i = 0; i < 32; ++i) {
        float2 ca = sm_cT2[i * 33 + r];   // broadcast within half-wave
        float2 cb = sm_cT2[i * 33 + s];   // contiguous, 2-way (free)
        float dx = ca.x - cb.x, dy = ca.y - cb.y;
        d2 = fmaf(dx, dx, d2);
        d2 = fmaf(dy, dy, d2);
    }
    float dm = active ? d2 : 3.4e38f;
#pragma unroll
    for (int off = 32; off > 0; off >>= 1) dm = fminf(dm, __shfl_down(dm, off, 64));
    if ((t & 63) == 0) red[t >> 6] = dm;
    __syncthreads();
    if (t < 64) {
        float v = (t < 16) ? red[t] : 3.4e38f;
#pragma unroll
        for (int off = 8; off > 0; off >>= 1) v = fminf(v, __shfl_down(v, off, 64));
        if (t == 0) dmin_sh = v;
    }
    if (t < RR) {  // cc from LDS
        float a2 = 0.f;
#pragma unroll
        for (int i = 0; i < 32; ++i) {
            float2 cv = sm_cT2[i * 33 + t];
            a2 = fmaf(cv.x, cv.x, a2);
            a2 = fmaf(cv.y, cv.y, a2);
        }
        cc[t] = a2;
    }
    __syncthreads();
    const float dmin = dmin_sh;
    if (active && d2 <= dmin + D2_CUT) {
        int idx = atomicAdd(&cnt, 1);
        plist[idx] = make_float2(fast_exp2(-d2 * LOG2E), __int_as_float(t));
    }
    __syncthreads();
    if (t == 0) *npairs = cnt;
}

// Champion (r4): block-phased sheaf, plain partials store + separate reduce.
// Session-proven invariants baked in:
//  - NO single-address device atomicAdd from 4096 blocks (~25 us far-atomic tail, r1/r2).
//  - NO per-block __threadfence(): device-scope release forces per-block L2
//    writeback on non-coherent XCDs (~+75 us, r9). Cross-block reduction goes
//    through the kernel boundary (single bulk flush) instead.
//  - NO forced low launch-bounds VGPR cap (spills 5 MB/dispatch, r1).
//  - LDS alias keeps block at 18.9 KB -> 8 blocks/CU by LDS; natural VGPR ~28.
__global__ __launch_bounds__(256) void sheaf2_kernel(
    const float* __restrict__ m, const float* __restrict__ w,
    const float* __restrict__ p, const float* __restrict__ c,
    const float* __restrict__ cc, const int* __restrict__ npairs,
    const float2* __restrict__ plist, float* __restrict__ partials) {
    // Alias zone: sm_pl (phase 4/5) overlaps cT2 (bytes 0-8447, phases 0-1) and
    // the staged m tile (bytes 8448-12543, phase 1). Lifetimes barrier-separated.
    __shared__ __align__(16) float2 sm_pl[RR * KK];  // 16384 B
    __shared__ float  sm_mass[PP * 36];              // 2304 B (pad 36: 16B-aligned rows)
    __shared__ float  sm_sw[PP];
    __shared__ float  sred[4];

    float2* sm_cT2 = sm_pl;                  // 32*33 float2 = 8448 B
    float*  sm_m   = (float*)sm_pl + 2112;   // byte offset 8448, 4096 B (16B-aligned)

    const int tid = threadIdx.x;
    const int bt  = blockIdx.x;
    const int kq  = tid & 63;

    // ---- entry prefetch: p column (16 regs) + np; latency hides under stage+ph1 ----
    const float* pg_ = p + (size_t)bt * PP * KK + kq;
    float pcol[PP];
#pragma unroll
    for (int pi = 0; pi < PP; ++pi) pcol[pi] = pg_[pi * KK];
    const int np = __builtin_amdgcn_readfirstlane(*npairs);

    // ---- stage: c transposed (4 KB), m tile (4 KB coalesced float4), w ----
    {
        const float2* c2 = (const float2*)c;  // [r][d2], 1024 entries
#pragma unroll
        for (int it = 0; it < 4; ++it) {
            int idx = tid + 256 * it;
            sm_cT2[(idx & 31) * 33 + (idx >> 5)] = c2[idx];
        }
        const float4* m4 = (const float4*)(m + (size_t)bt * PP * DD);
        ((float4*)sm_m)[tid] = m4[tid];
        if (tid < PP) sm_sw[tid] = w[(size_t)bt * PP + tid];
    }
    __syncthreads();

    // ---- phase 1: logits[p][r] = 2*m.c - ||c||^2 (||m||^2 cancels in softmax) ----
    {
        const int r  = tid & 31;
        const int pg = tid >> 5;  // 0..7; handles pi = pg and pg+8
        const float4* m4a = (const float4*)(sm_m + pg * DD);
        const float4* m4b = (const float4*)(sm_m + (pg + 8) * DD);
        float ccr = cc[r];
        float acc0 = 0.f, acc1 = 0.f;
#pragma unroll
        for (int d4 = 0; d4 < 16; ++d4) {
            float2 ca = sm_cT2[(2 * d4) * 33 + r];
            float2 cb = sm_cT2[(2 * d4 + 1) * 33 + r];
            float4 ma = m4a[d4];
            float4 mb = m4b[d4];
            acc0 = fmaf(ma.x, ca.x, acc0); acc0 = fmaf(ma.y, ca.y, acc0);
            acc0 = fmaf(ma.z, cb.x, acc0); acc0 = fmaf(ma.w, cb.y, acc0);
            acc1 = fmaf(mb.x, ca.x, acc1); acc1 = fmaf(mb.y, ca.y, acc1);
            acc1 = fmaf(mb.z, cb.x, acc1); acc1 = fmaf(mb.w, cb.y, acc1);
        }
        sm_mass[pg * 36 + r]       = fmaf(2.f, acc0, -ccr);
        sm_mass[(pg + 8) * 36 + r] = fmaf(2.f, acc1, -ccr);
    }
    __syncthreads();

    // ---- phase 2: per-p softmax over r, all 256 threads.
    //      16 lanes per p, 2 r each; shfl_xor reduce within 16-lane groups. ----
    {
        const int pidx = tid >> 4, l = tid & 15;
        float a = sm_mass[pidx * 36 + l];
        float b = sm_mass[pidx * 36 + l + 16];
        float mx = fmaxf(a, b);
#pragma unroll
        for (int off = 8; off > 0; off >>= 1) mx = fmaxf(mx, __shfl_xor(mx, off, 64));
        float ea = fast_exp2((a - mx) * LOG2E);
        float eb = fast_exp2((b - mx) * LOG2E);
        float ssum = ea + eb;
#pragma unroll
        for (int off = 8; off > 0; off >>= 1) ssum += __shfl_xor(ssum, off, 64);
        sm_mass[pidx * 36 + l]      = ea;
        sm_mass[pidx * 36 + l + 16] = eb;
        if (l == 0) sm_sw[pidx] = sm_sw[pidx] * fast_rcp(ssum);  // w / sum
    }
    __syncthreads();

    // ---- phase 3: mass[p][r] = e*sw[p] / (tot_r + eps); one full wave ----
    if (tid < 64) {
        const int r = tid & 31, h = tid >> 5;
        float ef[8];
        float tot = 0.f;
#pragma unroll
        for (int i = 0; i < 8; ++i) {
            ef[i] = sm_mass[(h * 8 + i) * 36 + r] * sm_sw[h * 8 + i];
            tot += ef[i];
        }
        tot += __shfl_xor(tot, 32, 64);
        float inv = fast_rcp(tot + 1e-6f);
#pragma unroll
        for (int i = 0; i < 8; ++i) sm_mass[(h * 8 + i) * 36 + r] = ef[i] * inv;
    }
    __syncthreads();

    // ---- phase 4: pbar[r][k]; store (pb, pb*log2 pb); overwrites cT2/m (dead) ----
    {
        const int wv = tid >> 6;
        const int r0 = wv * 8;
        float acc[8] = {0.f, 0.f, 0.f, 0.f, 0.f, 0.f, 0.f, 0.f};
#pragma unroll
        for (int pi = 0; pi < PP; ++pi) {
            float4 ma = *(const float4*)&sm_mass[pi * 36 + r0];      // wave-uniform bcast
            float4 mb = *(const float4*)&sm_mass[pi * 36 + r0 + 4];
            acc[0] = fmaf(pcol[pi], ma.x, acc[0]);
            acc[1] = fmaf(pcol[pi], ma.y, acc[1]);
            acc[2] = fmaf(pcol[pi], ma.z, acc[2]);
            acc[3] = fmaf(pcol[pi], ma.w, acc[3]);
            acc[4] = fmaf(pcol[pi], mb.x, acc[4]);
            acc[5] = fmaf(pcol[pi], mb.y, acc[5]);
            acc[6] = fmaf(pcol[pi], mb.z, acc[6]);
            acc[7] = fmaf(pcol[pi], mb.w, acc[7]);
        }
#pragma unroll
        for (int j = 0; j < 8; ++j) {
            float pb = acc[j];
            float l2 = fast_log2(pb + 1e-8f);
            sm_pl[(r0 + j) * KK + kq] = make_float2(pb, pb * l2);
        }
    }
    __syncthreads();

    // ---- phase 5: sum over pruned pairs of omega*[pr*l2pr + ps*l2ps - (pr+ps)*l2(mid)];
    //      plist loads wave-uniform -> s_load; 2 pairs/iter for ILP ----
    {
        const int wv = __builtin_amdgcn_readfirstlane(tid >> 6);
        float acc = 0.f;
        int i = wv;
        for (; i + 4 < np; i += 8) {
            float2 e0 = plist[i];
            float2 e1 = plist[i + 4];
            int rs0 = __float_as_int(e0.y);
            int rs1 = __float_as_int(e1.y);
            float2 a0 = sm_pl[(rs0 >> 5) * KK + kq];
            float2 b0 = sm_pl[(rs0 & 31) * KK + kq];
            float2 a1 = sm_pl[(rs1 >> 5) * KK + kq];
            float2 b1 = sm_pl[(rs1 & 31) * KK + kq];
            float s0 = a0.x + b0.x, t0 = a0.y + b0.y;
            float s1 = a1.x + b1.x, t1 = a1.y + b1.y;
            float lm0 = fast_log2(fmaf(0.5f, s0, 1e-8f));
            float lm1 = fast_log2(fmaf(0.5f, s1, 1e-8f));
            t0 = fmaf(-s0, lm0, t0);
            t1 = fmaf(-s1, lm1, t1);
            acc = fmaf(e0.x, t0, acc);
            acc = fmaf(e1.x, t1, acc);
        }
        if (i < np) {
            float2 e = plist[i];
            int rs = __float_as_int(e.y);
            float2 a = sm_pl[(rs >> 5) * KK + kq];
            float2 b = sm_pl[(rs & 31) * KK + kq];
            float sum = a.x + b.x;
            float t   = a.y + b.y;
            float lm  = fast_log2(fmaf(0.5f, sum, 1e-8f));
            t = fmaf(-sum, lm, t);
            acc = fmaf(e.x, t, acc);
        }
#pragma unroll
        for (int off = 32; off > 0; off >>= 1) acc += __shfl_down(acc, off, 64);
        if (kq == 0) sred[tid >> 6] = acc;
    }
    __syncthreads();
    if (tid == 0) {
        float tot = (sred[0] + sred[1]) + (sred[2] + sred[3]);
        partials[bt] = tot * (0.5f * LN2 / 496.0f);  // plain store, no atomic
    }
}

__global__ __launch_bounds__(256) void reduce_kernel(const float* __restrict__ partials,
                                                     float* __restrict__ out) {
    __shared__ float sred[4];
    const int tid = threadIdx.x;
    const float4* p4 = (const float4*)partials;  // 1024 float4
    float acc = 0.f;
#pragma unroll
    for (int i = 0; i < 4; ++i) {
        float4 v = p4[tid + 256 * i];
        acc += (v.x + v.y) + (v.z + v.w);
    }
#pragma unroll
    for (int off = 32; off > 0; off >>= 1) acc += __shfl_down(acc, off, 64);
    if ((tid & 63) == 0) sred[tid >> 6] = acc;
    __syncthreads();
    if (tid == 0) out[0] = (sred[0] + sred[1]) + (sred[2] + sred[3]);
}

extern "C" void kernel_launch(void* const* d_in, const int* in_sizes, int n_in,
                              void* d_out, int out_size, void* d_ws, size_t ws_size,
                              hipStream_t stream) {
    const float* m = (const float*)d_in[0];
    const float* w = (const float*)d_in[1];
    const float* p = (const float*)d_in[2];
    const float* c = (const float*)d_in[3];
    float* out = (float*)d_out;

    float* wsf      = (float*)d_ws;
    int*   npairs   = (int*)d_ws;            // [0]
    float* cc       = wsf + 64;              // 32 floats @ 256 B
    float2* plist   = (float2*)(wsf + 128);  // up to 496 float2 @ 512 B
    float* partials = wsf + 2048;            // 4096 floats @ 8 KB (16B-aligned)

    prune_kernel<<<1, 1024, 0, stream>>>(c, cc, npairs, plist);
    sheaf2_kernel<<<NBT, 256, 0, stream>>>(m, w, p, c, cc, npairs, plist, partials);
    reduce_kernel<<<1, 256, 0, stream>>>(partials, out);
}